// Round 4
// baseline (253.885 us; speedup 1.0000x reference)
//
#include <hip/hip_runtime.h>
#include <math.h>

// B,N,T,F = 32,512,12,64
#define BB 32
#define NN 512
#define TT 12
#define FF 64
#define PSTR 72            // P LDS stride in shorts

typedef float  f32x4   __attribute__((ext_vector_type(4)));
typedef float  f32x16  __attribute__((ext_vector_type(16)));
typedef short  short4v __attribute__((ext_vector_type(4)));
typedef short  short8v __attribute__((ext_vector_type(8)));
typedef unsigned int u32;
typedef u32    u32x4   __attribute__((ext_vector_type(4)));

static __device__ __forceinline__ short f2bf(float f) {
    u32 u = __builtin_bit_cast(u32, f);
    u32 r = u + 0x7FFFu + ((u >> 16) & 1u);   // RNE
    return (short)(r >> 16);
}
static __device__ __forceinline__ float bf2f(short h) {
    u32 u = ((u32)(unsigned short)h) << 16;
    return __builtin_bit_cast(float, u);
}

// ws layout (shorts): XRH[384][8][4096] | XRL | XTH | XTL | WH[4096] | WL[4096]
// tile image: element (row,col[shorts 0..63]) at row*64 + (col ^ (8*(row&7)))
#define WS_S ((size_t)384 * 32768)

// ---------------- pre-pass: convert+swizzle X into ws ----------------
__global__ __launch_bounds__(256)
void prep_x(const float* __restrict__ x, short* __restrict__ ws)
{
    __shared__ u32 sT[64][69];        // [m'][f], padded stride 69
    const int wg = blockIdx.x;        // 0..3071
    const int mt = wg & 7;
    const int bt = wg >> 3;
    const int t  = bt % TT;
    const int b  = bt / TT;
    const int m0 = mt * 64;
    const int tid = threadIdx.x;

    short* XRH = ws;
    short* XRL = ws + WS_S;
    short* XTH = ws + 2 * WS_S;
    short* XTL = ws + 3 * WS_S;
    const size_t tb = ((size_t)bt * 8 + mt) * 4096;

    #pragma unroll
    for (int k = 0; k < 4; ++k) {
        int idx = tid + k * 256;
        int row = idx >> 4;
        int c4  = (idx & 15) << 2;
        f32x4 xv = *(const f32x4*)(x + (((size_t)(b * NN + m0 + row) * TT + t) * FF) + c4);
        short4v h, lo;
        #pragma unroll
        for (int j = 0; j < 4; ++j) {
            short hh = f2bf(xv[j]);
            h[j]  = hh;
            lo[j] = f2bf(xv[j] - bf2f(hh));
        }
        int cs = c4 ^ ((row & 7) << 3);
        *(short4v*)&XRH[tb + row * 64 + cs] = h;
        *(short4v*)&XRL[tb + row * 64 + cs] = lo;
        #pragma unroll
        for (int j = 0; j < 4; ++j)
            sT[row][c4 + j] = ((u32)(unsigned short)h[j] << 16) | (u32)(unsigned short)lo[j];
    }
    __syncthreads();
    #pragma unroll
    for (int k = 0; k < 2; ++k) {
        int u  = tid + k * 256;       // 0..511
        int f  = u >> 3;              // 0..63
        int mB = u & 7;               // 8-m' block
        short8v H, L;
        #pragma unroll
        for (int j = 0; j < 8; ++j) {
            u32 pk = sT[mB * 8 + j][f];
            H[j] = (short)(pk >> 16);
            L[j] = (short)(pk & 0xffffu);
        }
        int cs = (mB ^ (f & 7)) << 3;
        *(short8v*)&XTH[tb + f * 64 + cs] = H;
        *(short8v*)&XTL[tb + f * 64 + cs] = L;
    }
}

__global__ __launch_bounds__(256)
void prep_w(const float* __restrict__ W, short* __restrict__ ws)
{
    short* WH = ws + 4 * WS_S;
    short* WL = WH + 4096;
    const int tid = threadIdx.x;
    #pragma unroll
    for (int k = 0; k < 4; ++k) {
        int idx = tid + k * 256;
        int row = idx >> 4;
        int c4  = (idx & 15) << 2;
        f32x4 wv = *(const f32x4*)(W + row * FF + c4);
        short4v h, lo;
        #pragma unroll
        for (int j = 0; j < 4; ++j) {
            short hh = f2bf(wv[j]);
            h[j]  = hh;
            lo[j] = f2bf(wv[j] - bf2f(hh));
        }
        int cs = c4 ^ ((row & 7) << 3);
        *(short4v*)&WH[row * 64 + cs] = h;
        *(short4v*)&WL[row * 64 + cs] = lo;
    }
}

// ---------------- main fused kernel: 128 rows/WG, 32x32x16 MFMA ----------------
__global__ __launch_bounds__(256, 3)
void sgcn_main(const float* __restrict__ x, const float* __restrict__ adj,
               const short* __restrict__ ws, float* __restrict__ out)
{
    // [0:4096) RH | [4096:8192) RL | [8192:12288) TH | [12288:16384) TL  (32 KB)
    // epilogue reuse: A-hi [0:8192), A-lo [8192:16384)
    __shared__ __align__(16) short sTile[16384];
    __shared__ __align__(16) short sP[128 * PSTR];   // P; epilogue: WH||WL

    // XCD-grouped swizzle: 1536 WGs, 4 members per (b,t) temporally adjacent per XCD
    const int d   = blockIdx.x;
    const int xcd = d & 7;
    const int s   = d >> 3;               // 0..191
    const int G   = xcd + 8 * (s >> 2);   // 0..383 = b*12+t
    const int mem = s & 3;
    const int t = G % TT, b = G / TT;
    const int n0 = mem * 128;

    const int tid = threadIdx.x;
    const int w   = tid >> 6;
    const int l   = tid & 63;
    const int l31 = l & 31;
    const int hi2 = l >> 5;
    const int l7  = l & 7;

    const float KEXP = 0.18033688011112042f;   // 0.125 * log2(e)

    // Xn A-fragments (rows 32w+l31), hi/lo, once from fp32 x
    short8v aH[4], aL[4];
    {
        const float* xr = x + (((size_t)(b * NN + n0 + 32 * w + l31) * TT + t) * FF);
        #pragma unroll
        for (int ks = 0; ks < 4; ++ks) {
            f32x4 x0 = *(const f32x4*)(xr + ks * 16 + hi2 * 8);
            f32x4 x1 = *(const f32x4*)(xr + ks * 16 + hi2 * 8 + 4);
            #pragma unroll
            for (int j = 0; j < 4; ++j) {
                short hh = f2bf(x0[j]);
                aH[ks][j] = hh;
                aL[ks][j] = f2bf(x0[j] - bf2f(hh));
            }
            #pragma unroll
            for (int j = 0; j < 4; ++j) {
                short hh = f2bf(x1[j]);
                aH[ks][4 + j] = hh;
                aL[ks][4 + j] = f2bf(x1[j] - bf2f(hh));
            }
        }
    }

    f32x16 agg0, agg1;
    float l_part[16];
    #pragma unroll
    for (int i = 0; i < 16; ++i) { agg0[i] = 0.f; agg1[i] = 0.f; l_part[i] = 0.f; }

    const size_t btb = (size_t)G * 32768;

    for (int mt = 0; mt < 8; ++mt) {
        const size_t tbase = btb + (size_t)mt * 4096;
        // stage 32 KB (4 arrays x 8 KB), linear 16-B copies, pre-swizzled source
        #pragma unroll
        for (int a = 0; a < 4; ++a)
            #pragma unroll
            for (int k = 0; k < 2; ++k) {
                int o = tid * 8 + k * 2048;
                *(u32x4*)&sTile[a * 4096 + o] = *(const u32x4*)&ws[a * WS_S + tbase + o];
            }
        const int m0 = mt * 64;
        __syncthreads();

        // ---- S = Xn*Xm^T (3-term hi/lo) + maxless softmax, per 32-col block ----
        #pragma unroll
        for (int cb = 0; cb < 2; ++cb) {
            float av[16];
            #pragma unroll
            for (int rr = 0; rr < 16; ++rr) {
                int row = (rr & 3) + 8 * (rr >> 2) + 4 * hi2;
                av[rr] = adj[(size_t)(n0 + 32 * w + row) * NN + m0 + 32 * cb + l31];
            }
            f32x16 sc;
            #pragma unroll
            for (int i = 0; i < 16; ++i) sc[i] = 0.f;
            #pragma unroll
            for (int ks = 0; ks < 4; ++ks) {
                int co = ((2 * ks + hi2) ^ l7) << 3;
                short8v bH = *(const short8v*)&sTile[(32 * cb + l31) * 64 + co];
                short8v bL = *(const short8v*)&sTile[4096 + (32 * cb + l31) * 64 + co];
                sc = __builtin_amdgcn_mfma_f32_32x32x16_bf16(aH[ks], bH, sc, 0, 0, 0);
                sc = __builtin_amdgcn_mfma_f32_32x32x16_bf16(aH[ks], bL, sc, 0, 0, 0);
                sc = __builtin_amdgcn_mfma_f32_32x32x16_bf16(aL[ks], bH, sc, 0, 0, 0);
            }
            #pragma unroll
            for (int rr = 0; rr < 16; rr += 2) {
                float p0 = exp2f(sc[rr]     * KEXP);
                float p1 = exp2f(sc[rr + 1] * KEXP);
                l_part[rr]     += p0;            // denominator WITHOUT adj (post-softmax mask)
                l_part[rr + 1] += p1;
                p0 *= av[rr];
                p1 *= av[rr + 1];
                u32 pk;
                asm("v_cvt_pk_bf16_f32 %0, %1, %2" : "=v"(pk) : "v"(p0), "v"(p1));
                int row0 = (rr & 3) + 8 * (rr >> 2) + 4 * hi2 + 32 * w;
                sP[row0 * PSTR + 32 * cb + l31]       = (short)(pk & 0xffffu);
                sP[(row0 + 1) * PSTR + 32 * cb + l31] = (short)(pk >> 16);
            }
        }

        // ---- PV: agg += P * V (V hi/lo from transposed tile) ----
        short8v pa[4];
        #pragma unroll
        for (int ks = 0; ks < 4; ++ks)
            pa[ks] = *(const short8v*)&sP[(32 * w + l31) * PSTR + ks * 16 + hi2 * 8];
        #pragma unroll
        for (int ks = 0; ks < 4; ++ks) {
            int co = ((2 * ks + hi2) ^ l7) << 3;
            short8v vH0 = *(const short8v*)&sTile[8192  + l31 * 64 + co];
            short8v vL0 = *(const short8v*)&sTile[12288 + l31 * 64 + co];
            agg0 = __builtin_amdgcn_mfma_f32_32x32x16_bf16(pa[ks], vH0, agg0, 0, 0, 0);
            agg0 = __builtin_amdgcn_mfma_f32_32x32x16_bf16(pa[ks], vL0, agg0, 0, 0, 0);
            short8v vH1 = *(const short8v*)&sTile[8192  + (32 + l31) * 64 + co];
            short8v vL1 = *(const short8v*)&sTile[12288 + (32 + l31) * 64 + co];
            agg1 = __builtin_amdgcn_mfma_f32_32x32x16_bf16(pa[ks], vH1, agg1, 0, 0, 0);
            agg1 = __builtin_amdgcn_mfma_f32_32x32x16_bf16(pa[ks], vL1, agg1, 0, 0, 0);
        }
        __syncthreads();
    }

    // ---- deferred l reduction (cols live across the 32 lanes of each half) ----
    #pragma unroll
    for (int rr = 0; rr < 16; ++rr) {
        float v = l_part[rr];
        v += __shfl_xor(v, 1);
        v += __shfl_xor(v, 2);
        v += __shfl_xor(v, 4);
        v += __shfl_xor(v, 8);
        v += __shfl_xor(v, 16);
        l_part[rr] = 0.125f / v;     // fold post-softmax 1/8 scale
    }

    // ---- epilogue: A = agg*nrm (hi/lo) -> LDS; stage W; out = relu(A*W^T) ----
    #pragma unroll
    for (int cf = 0; cf < 2; ++cf) {
        #pragma unroll
        for (int rr = 0; rr < 16; ++rr) {
            float v = (cf ? agg1[rr] : agg0[rr]) * l_part[rr];
            short hh = f2bf(v);
            short ll = f2bf(v - bf2f(hh));
            int row = (rr & 3) + 8 * (rr >> 2) + 4 * hi2 + 32 * w;
            int cs  = (32 * cf + l31) ^ ((row & 7) << 3);
            sTile[row * 64 + cs]        = hh;
            sTile[8192 + row * 64 + cs] = ll;
        }
    }
    {
        const short* wsW = ws + 4 * WS_S;
        #pragma unroll
        for (int k = 0; k < 4; ++k) {
            int o = tid * 8 + k * 2048;
            *(u32x4*)&sP[o] = *(const u32x4*)&wsW[o];
        }
    }
    __syncthreads();

    short8v gH[4], gL[4];
    #pragma unroll
    for (int ks = 0; ks < 4; ++ks) {
        int co = ((2 * ks + hi2) ^ l7) << 3;
        gH[ks] = *(const short8v*)&sTile[(32 * w + l31) * 64 + co];
        gL[ks] = *(const short8v*)&sTile[8192 + (32 * w + l31) * 64 + co];
    }
    #pragma unroll
    for (int co2 = 0; co2 < 2; ++co2) {
        f32x16 oc;
        #pragma unroll
        for (int i = 0; i < 16; ++i) oc[i] = 0.f;
        #pragma unroll
        for (int ks = 0; ks < 4; ++ks) {
            int cc = ((2 * ks + hi2) ^ l7) << 3;
            short8v wH = *(const short8v*)&sP[(32 * co2 + l31) * 64 + cc];
            short8v wL = *(const short8v*)&sP[4096 + (32 * co2 + l31) * 64 + cc];
            oc = __builtin_amdgcn_mfma_f32_32x32x16_bf16(gH[ks], wH, oc, 0, 0, 0);
            oc = __builtin_amdgcn_mfma_f32_32x32x16_bf16(gH[ks], wL, oc, 0, 0, 0);
            oc = __builtin_amdgcn_mfma_f32_32x32x16_bf16(gL[ks], wH, oc, 0, 0, 0);
        }
        #pragma unroll
        for (int rr = 0; rr < 16; ++rr) {
            int row = (rr & 3) + 8 * (rr >> 2) + 4 * hi2;
            out[(((size_t)(b * NN + n0 + 32 * w + row) * TT + t) * FF) + 32 * co2 + l31] =
                fmaxf(oc[rr], 0.f);
        }
    }
}

// ---------------- fallback (round-3 kernel) if ws too small ----------------
#define ROWS 64
#define MT 64
#define NTILES (NN / MT)
#define LDH 72
#define LDT 68

__global__ __launch_bounds__(256, 3)
void sgcn_mfma2(const float* __restrict__ x,
                const float* __restrict__ adj,
                const float* __restrict__ W,
                float* __restrict__ out)
{
    __shared__ __align__(16) short sKH [MT][LDH], sKL [MT][LDH];
    __shared__ __align__(16) short sKTH[FF][LDT], sKTL[FF][LDT];
    __shared__ __align__(16) short sPH [ROWS][LDH];

    const int wg = blockIdx.x;
    const int nb = wg & 7;
    const int bt = wg >> 3;
    const int t  = bt % TT;
    const int b  = bt / TT;
    const int n0 = nb * ROWS;

    const int tid  = threadIdx.x;
    const int w    = tid >> 6;
    const int l    = tid & 63;
    const int lm   = l & 15;
    const int hi4  = l >> 4;
    const int koff = hi4 * 8;

    short8v aH[2], aL[2];
    {
        const float* xrow = x + (((size_t)(b * NN + n0 + 16 * w + lm) * TT + t) * FF);
        #pragma unroll
        for (int ks = 0; ks < 2; ++ks) {
            f32x4 x0 = *(const f32x4*)(xrow + ks * 32 + koff);
            f32x4 x1 = *(const f32x4*)(xrow + ks * 32 + koff + 4);
            #pragma unroll
            for (int j = 0; j < 4; ++j) {
                short hh = f2bf(x0[j]);
                aH[ks][j] = hh;
                aL[ks][j] = f2bf(x0[j] - bf2f(hh));
            }
            #pragma unroll
            for (int j = 0; j < 4; ++j) {
                short hh = f2bf(x1[j]);
                aH[ks][4 + j] = hh;
                aL[ks][4 + j] = f2bf(x1[j] - bf2f(hh));
            }
        }
    }

    f32x4 agg[4];
    #pragma unroll
    for (int c = 0; c < 4; ++c) { agg[c][0]=0.f; agg[c][1]=0.f; agg[c][2]=0.f; agg[c][3]=0.f; }
    float m_run[4], l_run[4], fac[4];
    #pragma unroll
    for (int r = 0; r < 4; ++r) { m_run[r] = -INFINITY; l_run[r] = 0.f; }

    const float* adjbase = adj + (size_t)(n0 + 16 * w + 4 * hi4) * NN + lm;

    for (int mt = 0; mt < NTILES; ++mt) {
        const int m0 = mt * MT;
        #pragma unroll
        for (int k = 0; k < 4; ++k) {
            int idx = tid + k * 256;
            int row = idx >> 4;
            int c4  = (idx & 15) << 2;
            f32x4 xv = *(const f32x4*)(x + (((size_t)(b * NN + m0 + row) * TT + t) * FF) + c4);
            short4v h, lo;
            #pragma unroll
            for (int j = 0; j < 4; ++j) {
                short hh = f2bf(xv[j]);
                h[j]  = hh;
                lo[j] = f2bf(xv[j] - bf2f(hh));
            }
            *(short4v*)&sKH[row][c4] = h;
            *(short4v*)&sKL[row][c4] = lo;
            #pragma unroll
            for (int j = 0; j < 4; ++j) {
                sKTH[c4 + j][row] = h[j];
                sKTL[c4 + j][row] = lo[j];
            }
        }
        float adjv[4][4];
        #pragma unroll
        for (int c = 0; c < 4; ++c)
            #pragma unroll
            for (int r = 0; r < 4; ++r)
                adjv[c][r] = adjbase[(size_t)r * NN + m0 + 16 * c];
        __syncthreads();

        f32x4 sc[4];
        #pragma unroll
        for (int c = 0; c < 4; ++c) {
            f32x4 acc; acc[0]=0.f; acc[1]=0.f; acc[2]=0.f; acc[3]=0.f;
            #pragma unroll
            for (int ks = 0; ks < 2; ++ks) {
                short8v bH = *(const short8v*)&sKH[16 * c + lm][ks * 32 + koff];
                short8v bL = *(const short8v*)&sKL[16 * c + lm][ks * 32 + koff];
                acc = __builtin_amdgcn_mfma_f32_16x16x32_bf16(aH[ks], bH, acc, 0, 0, 0);
                acc = __builtin_amdgcn_mfma_f32_16x16x32_bf16(aH[ks], bL, acc, 0, 0, 0);
                acc = __builtin_amdgcn_mfma_f32_16x16x32_bf16(aL[ks], bH, acc, 0, 0, 0);
            }
            sc[c] = acc;
        }
        #pragma unroll
        for (int r = 0; r < 4; ++r) {
            float mx = fmaxf(fmaxf(sc[0][r], sc[1][r]), fmaxf(sc[2][r], sc[3][r]));
            mx = fmaxf(mx, __shfl_xor(mx, 1));
            mx = fmaxf(mx, __shfl_xor(mx, 2));
            mx = fmaxf(mx, __shfl_xor(mx, 4));
            mx = fmaxf(mx, __shfl_xor(mx, 8));
            mx *= 0.125f;
            float mn = fmaxf(m_run[r], mx);
            fac[r] = __expf(m_run[r] - mn);
            m_run[r] = mn;
            float ls = 0.f;
            #pragma unroll
            for (int c = 0; c < 4; ++c) {
                float e = __expf(sc[c][r] * 0.125f - mn);
                ls += e;
                float p = e * adjv[c][r];
                sPH[16 * w + 4 * hi4 + r][16 * c + lm] = f2bf(p);
            }
            ls += __shfl_xor(ls, 1);
            ls += __shfl_xor(ls, 2);
            ls += __shfl_xor(ls, 4);
            ls += __shfl_xor(ls, 8);
            l_run[r] = l_run[r] * fac[r] + ls;
        }
        short8v pH[2];
        #pragma unroll
        for (int ks = 0; ks < 2; ++ks)
            pH[ks] = *(const short8v*)&sPH[16 * w + lm][ks * 32 + koff];
        #pragma unroll
        for (int c2 = 0; c2 < 4; ++c2) {
            #pragma unroll
            for (int r = 0; r < 4; ++r) agg[c2][r] *= fac[r];
            #pragma unroll
            for (int ks = 0; ks < 2; ++ks) {
                short4v h0 = *(const short4v*)&sKTH[16 * c2 + lm][ks * 32 + koff];
                short4v h1 = *(const short4v*)&sKTH[16 * c2 + lm][ks * 32 + koff + 4];
                short4v l0 = *(const short4v*)&sKTL[16 * c2 + lm][ks * 32 + koff];
                short4v l1 = *(const short4v*)&sKTL[16 * c2 + lm][ks * 32 + koff + 4];
                short8v bH = __builtin_shufflevector(h0, h1, 0,1,2,3,4,5,6,7);
                short8v bL = __builtin_shufflevector(l0, l1, 0,1,2,3,4,5,6,7);
                agg[c2] = __builtin_amdgcn_mfma_f32_16x16x32_bf16(pH[ks], bH, agg[c2], 0, 0, 0);
                agg[c2] = __builtin_amdgcn_mfma_f32_16x16x32_bf16(pH[ks], bL, agg[c2], 0, 0, 0);
            }
        }
        __syncthreads();
    }

    #pragma unroll
    for (int k = 0; k < 4; ++k) {
        int idx = tid + k * 256;
        int row = idx >> 4;
        int c4  = (idx & 15) << 2;
        f32x4 wv = *(const f32x4*)(W + row * FF + c4);
        short4v h, lo;
        #pragma unroll
        for (int j = 0; j < 4; ++j) {
            short hh = f2bf(wv[j]);
            h[j]  = hh;
            lo[j] = f2bf(wv[j] - bf2f(hh));
        }
        *(short4v*)&sKH[row][c4] = h;
        *(short4v*)&sKL[row][c4] = lo;
    }
    float nrm[4];
    #pragma unroll
    for (int r = 0; r < 4; ++r) nrm[r] = 0.125f / l_run[r];
    #pragma unroll
    for (int c2 = 0; c2 < 4; ++c2)
        #pragma unroll
        for (int r = 0; r < 4; ++r) {
            float v = agg[c2][r] * nrm[r];
            short hh = f2bf(v);
            sPH [16 * w + 4 * hi4 + r][16 * c2 + lm] = hh;
            sKTH[16 * w + 4 * hi4 + r][16 * c2 + lm] = f2bf(v - bf2f(hh));
        }
    __syncthreads();

    short8v gH[2], gL[2];
    #pragma unroll
    for (int ks = 0; ks < 2; ++ks) {
        gH[ks] = *(const short8v*)&sPH[16 * w + lm][ks * 32 + koff];
        short4v g0 = *(const short4v*)&sKTH[16 * w + lm][ks * 32 + koff];
        short4v g1 = *(const short4v*)&sKTH[16 * w + lm][ks * 32 + koff + 4];
        gL[ks] = __builtin_shufflevector(g0, g1, 0,1,2,3,4,5,6,7);
    }
    float* obase = out + (((size_t)(b * NN + n0 + 16 * w + 4 * hi4) * TT + t) * FF) + lm;
    #pragma unroll
    for (int c2 = 0; c2 < 4; ++c2) {
        f32x4 acc; acc[0]=0.f; acc[1]=0.f; acc[2]=0.f; acc[3]=0.f;
        #pragma unroll
        for (int ks = 0; ks < 2; ++ks) {
            short8v bH = *(const short8v*)&sKH[16 * c2 + lm][ks * 32 + koff];
            short8v bL = *(const short8v*)&sKL[16 * c2 + lm][ks * 32 + koff];
            acc = __builtin_amdgcn_mfma_f32_16x16x32_bf16(gH[ks], bH, acc, 0, 0, 0);
            acc = __builtin_amdgcn_mfma_f32_16x16x32_bf16(gH[ks], bL, acc, 0, 0, 0);
            acc = __builtin_amdgcn_mfma_f32_16x16x32_bf16(gL[ks], bH, acc, 0, 0, 0);
        }
        #pragma unroll
        for (int r = 0; r < 4; ++r)
            obase[(size_t)r * TT * FF + 16 * c2] = fmaxf(acc[r], 0.f);
    }
}

extern "C" void kernel_launch(void* const* d_in, const int* in_sizes, int n_in,
                              void* d_out, int out_size, void* d_ws, size_t ws_size,
                              hipStream_t stream) {
    const float* x   = (const float*)d_in[0];
    const float* adj = (const float*)d_in[1];
    const float* W   = (const float*)d_in[2];
    float* outp = (float*)d_out;

    const size_t need = (4 * WS_S + 8192) * sizeof(short);   // ~100.7 MB
    if (ws_size >= need) {
        short* ws = (short*)d_ws;
        prep_x<<<dim3(3072), dim3(256), 0, stream>>>(x, ws);
        prep_w<<<dim3(1), dim3(256), 0, stream>>>(W, ws);
        sgcn_main<<<dim3(1536), dim3(256), 0, stream>>>(x, adj, ws, outp);
    } else {
        sgcn_mfma2<<<dim3(3072), dim3(256), 0, stream>>>(x, adj, W, outp);
    }
}

// Round 6
// 195.187 us; speedup vs baseline: 1.3007x; 1.3007x over previous
//
#include <hip/hip_runtime.h>
#include <math.h>

// B,N,T,F = 32,512,12,64
#define NN 512
#define TT 12
#define FF 64

typedef float  f32x4   __attribute__((ext_vector_type(4)));
typedef float  f32x16  __attribute__((ext_vector_type(16)));
typedef short  short4v __attribute__((ext_vector_type(4)));
typedef short  short8v __attribute__((ext_vector_type(8)));
typedef unsigned int u32;
typedef u32    u32x2   __attribute__((ext_vector_type(2)));

static __device__ __forceinline__ u32 cvtpk(float a, float b) {
    u32 p;
    asm("v_cvt_pk_bf16_f32 %0, %1, %2" : "=v"(p) : "v"(a), "v"(b));
    return p;   // low16 = bf16(a), high16 = bf16(b)   [verified: round-4 passed]
}
static __device__ __forceinline__ short f2bf(float f) {
    u32 u = __builtin_bit_cast(u32, f);
    u32 r = u + 0x7FFFu + ((u >> 16) & 1u);   // RNE
    return (short)(r >> 16);
}
static __device__ __forceinline__ float bf2f(short h) {
    u32 u = ((u32)(unsigned short)h) << 16;
    return __builtin_bit_cast(float, u);
}
// 4 floats -> bf16 hi + exact-residual bf16 lo (2x fewer VALU than manual path)
static __device__ __forceinline__ void cvt4(f32x4 v, short4v& h, short4v& lo) {
    u32 p01 = cvtpk(v[0], v[1]);
    u32 p23 = cvtpk(v[2], v[3]);
    float r0 = v[0] - __builtin_bit_cast(float, p01 << 16);
    float r1 = v[1] - __builtin_bit_cast(float, p01 & 0xffff0000u);
    float r2 = v[2] - __builtin_bit_cast(float, p23 << 16);
    float r3 = v[3] - __builtin_bit_cast(float, p23 & 0xffff0000u);
    u32 q01 = cvtpk(r0, r1);
    u32 q23 = cvtpk(r2, r3);
    u32x2 hh; hh[0] = p01; hh[1] = p23;
    u32x2 qq; qq[0] = q01; qq[1] = q23;
    h  = __builtin_bit_cast(short4v, hh);
    lo = __builtin_bit_cast(short4v, qq);
}
static __device__ __forceinline__ short8v cat44(short4v a, short4v b) {
    return __builtin_shufflevector(a, b, 0, 1, 2, 3, 4, 5, 6, 7);
}

// LDS map (bytes), SMEM = 54272 -> 3 blocks/CU (162816 <= 163840)
//  main loop : sKH [64][72] @0      sKL @9216      (row-major K tile, b128-aligned)
//              sKTH[64][68] @18432  sKTL @27136    (f-major V tile, b64-aligned)
//              sPH [128][72] @35840                (P hi, b128-aligned)
//  epilogue  : sAH [128][68] @0     sAL @17408     (normalized agg hi/lo)
//              sWH [64][72] @34816  sWL @44032
#define SMEM_BYTES 54272

__global__ __launch_bounds__(256, 3)
void sgcn6(const float* __restrict__ x, const float* __restrict__ adj,
           const float* __restrict__ W, float* __restrict__ out)
{
    __shared__ __align__(16) char smem[SMEM_BYTES];
    char* sKH  = smem;
    char* sKL  = smem + 9216;
    char* sKTH = smem + 18432;
    char* sKTL = smem + 27136;
    char* sPH  = smem + 35840;
    char* sAH  = smem;
    char* sAL  = smem + 17408;
    char* sWH  = smem + 34816;
    char* sWL  = smem + 44032;

    // XCD-grouped swizzle (round-4 mapping): 4 WGs per (b,t) adjacent on one XCD
    const int d   = blockIdx.x;
    const int xcd = d & 7;
    const int s   = d >> 3;
    const int G   = xcd + 8 * (s >> 2);   // 0..383 = b*12 + t
    const int mem = s & 3;
    const int t = G % TT, b = G / TT;
    const int n0 = mem * 128;

    const int tid = threadIdx.x;
    const int w   = tid >> 6;             // wave 0..3 -> n-rows 32w..32w+31
    const int l31 = tid & 31;
    const int hi2 = (tid >> 5) & 1;

    // staging map: thread owns rows 4mq..4mq+3, floats 4fq..4fq+3
    const int fq = tid & 15;
    const int mq = tid >> 4;

    const float K2 = 0.18033688011112042f;   // 0.125 * log2(e)

#define STAGE_WRITE(L0, L1, L2, L3)                                            \
  {                                                                            \
    short4v h0,q0,h1,q1,h2,q2,h3,q3;                                           \
    cvt4(L0,h0,q0); cvt4(L1,h1,q1); cvt4(L2,h2,q2); cvt4(L3,h3,q3);            \
    *(short4v*)(sKH + ((4*mq+0)*72 + 4*fq) * 2) = h0;                          \
    *(short4v*)(sKH + ((4*mq+1)*72 + 4*fq) * 2) = h1;                          \
    *(short4v*)(sKH + ((4*mq+2)*72 + 4*fq) * 2) = h2;                          \
    *(short4v*)(sKH + ((4*mq+3)*72 + 4*fq) * 2) = h3;                          \
    *(short4v*)(sKL + ((4*mq+0)*72 + 4*fq) * 2) = q0;                          \
    *(short4v*)(sKL + ((4*mq+1)*72 + 4*fq) * 2) = q1;                          \
    *(short4v*)(sKL + ((4*mq+2)*72 + 4*fq) * 2) = q2;                          \
    *(short4v*)(sKL + ((4*mq+3)*72 + 4*fq) * 2) = q3;                          \
    _Pragma("unroll")                                                          \
    for (int j = 0; j < 4; ++j) {                                              \
        short4v th; th[0]=h0[j]; th[1]=h1[j]; th[2]=h2[j]; th[3]=h3[j];        \
        short4v tl; tl[0]=q0[j]; tl[1]=q1[j]; tl[2]=q2[j]; tl[3]=q3[j];        \
        *(short4v*)(sKTH + ((4*fq+j)*68 + 4*mq) * 2) = th;                     \
        *(short4v*)(sKTL + ((4*fq+j)*68 + 4*mq) * 2) = tl;                     \
    }                                                                          \
  }

    // ---- prologue: Xn A-fragments (rows n0+32w+l31) + tile-0 staging ----
    const float* xnrow = x + ((size_t)(b * NN + n0 + 32 * w + l31) * TT + t) * FF;
    f32x4 xa[8];
    #pragma unroll
    for (int ks = 0; ks < 4; ++ks) {
        xa[2*ks]   = *(const f32x4*)(xnrow + ks * 16 + hi2 * 8);
        xa[2*ks+1] = *(const f32x4*)(xnrow + ks * 16 + hi2 * 8 + 4);
    }
    const float* xst = x + ((size_t)(b * NN + 4 * mq) * TT + t) * FF + 4 * fq;
    f32x4 ld0 = *(const f32x4*)(xst);
    f32x4 ld1 = *(const f32x4*)(xst + TT * FF);
    f32x4 ld2 = *(const f32x4*)(xst + 2 * TT * FF);
    f32x4 ld3 = *(const f32x4*)(xst + 3 * TT * FF);

    short8v xnH[4], xnL[4];
    #pragma unroll
    for (int ks = 0; ks < 4; ++ks) {
        short4v h0, l0, h1, l1;
        cvt4(xa[2*ks],   h0, l0);
        cvt4(xa[2*ks+1], h1, l1);
        xnH[ks] = cat44(h0, h1);
        xnL[ks] = cat44(l0, l1);
    }
    STAGE_WRITE(ld0, ld1, ld2, ld3)
    __syncthreads();

    float lp[16];
    #pragma unroll
    for (int i = 0; i < 16; ++i) lp[i] = 0.f;
    f32x16 agg0, agg1;
    #pragma unroll
    for (int i = 0; i < 16; ++i) { agg0[i] = 0.f; agg1[i] = 0.f; }

    for (int mt = 0; mt < 8; ++mt) {
        const int m0 = mt * 64;

        // T14: issue next-tile loads now; convert+write after the barrier
        f32x4 p0, p1, p2, p3;
        if (mt < 7) {
            const float* xs = x + ((size_t)(b * NN + m0 + 64 + 4 * mq) * TT + t) * FF + 4 * fq;
            p0 = *(const f32x4*)(xs);
            p1 = *(const f32x4*)(xs + TT * FF);
            p2 = *(const f32x4*)(xs + 2 * TT * FF);
            p3 = *(const f32x4*)(xs + 3 * TT * FF);
        }

        // ---- S = Xn*Xm^T (3-term hi/lo) + maxless softmax, per 32-m block ----
        #pragma unroll
        for (int cb = 0; cb < 2; ++cb) {
            const float* abase = adj + (size_t)(n0 + 32 * w + 4 * hi2) * NN + m0 + 32 * cb + l31;
            float av[16];
            #pragma unroll
            for (int r = 0; r < 16; ++r)
                av[r] = abase[(size_t)((r & 3) + 8 * (r >> 2)) * NN];

            f32x16 sc;
            #pragma unroll
            for (int i = 0; i < 16; ++i) sc[i] = 0.f;
            #pragma unroll
            for (int ks = 0; ks < 4; ++ks) {
                short8v bH = *(const short8v*)(sKH + ((32*cb + l31) * 72 + ks*16 + hi2*8) * 2);
                short8v bL = *(const short8v*)(sKL + ((32*cb + l31) * 72 + ks*16 + hi2*8) * 2);
                sc = __builtin_amdgcn_mfma_f32_32x32x16_bf16(xnH[ks], bH, sc, 0, 0, 0);
                sc = __builtin_amdgcn_mfma_f32_32x32x16_bf16(xnH[ks], bL, sc, 0, 0, 0);
                sc = __builtin_amdgcn_mfma_f32_32x32x16_bf16(xnL[ks], bH, sc, 0, 0, 0);
            }
            #pragma unroll
            for (int r = 0; r < 16; ++r) {
                float e = exp2f(sc[r] * K2);
                lp[r] += e;                      // denominator WITHOUT adj (post-softmax mask)
                float p = e * av[r];
                int row = 32 * w + (r & 3) + 8 * (r >> 2) + 4 * hi2;
                *(short*)(sPH + (row * 72 + 32 * cb + l31) * 2) = f2bf(p);
            }
        }

        // ---- PV: agg[n][f] += P * V (B-frags = row reads of f-major tile) ----
        short8v pa[4];
        #pragma unroll
        for (int ks = 0; ks < 4; ++ks)
            pa[ks] = *(const short8v*)(sPH + ((32*w + l31) * 72 + ks*16 + hi2*8) * 2);

        #pragma unroll
        for (int ks = 0; ks < 4; ++ks) {
            {   // f-block 0 -> agg0
                short4v v0 = *(const short4v*)(sKTH + (l31 * 68 + ks*16 + hi2*8) * 2);
                short4v v1 = *(const short4v*)(sKTH + (l31 * 68 + ks*16 + hi2*8 + 4) * 2);
                short4v u0 = *(const short4v*)(sKTL + (l31 * 68 + ks*16 + hi2*8) * 2);
                short4v u1 = *(const short4v*)(sKTL + (l31 * 68 + ks*16 + hi2*8 + 4) * 2);
                agg0 = __builtin_amdgcn_mfma_f32_32x32x16_bf16(pa[ks], cat44(v0, v1), agg0, 0, 0, 0);
                agg0 = __builtin_amdgcn_mfma_f32_32x32x16_bf16(pa[ks], cat44(u0, u1), agg0, 0, 0, 0);
            }
            {   // f-block 1 -> agg1
                short4v v0 = *(const short4v*)(sKTH + ((32 + l31) * 68 + ks*16 + hi2*8) * 2);
                short4v v1 = *(const short4v*)(sKTH + ((32 + l31) * 68 + ks*16 + hi2*8 + 4) * 2);
                short4v u0 = *(const short4v*)(sKTL + ((32 + l31) * 68 + ks*16 + hi2*8) * 2);
                short4v u1 = *(const short4v*)(sKTL + ((32 + l31) * 68 + ks*16 + hi2*8 + 4) * 2);
                agg1 = __builtin_amdgcn_mfma_f32_32x32x16_bf16(pa[ks], cat44(v0, v1), agg1, 0, 0, 0);
                agg1 = __builtin_amdgcn_mfma_f32_32x32x16_bf16(pa[ks], cat44(u0, u1), agg1, 0, 0, 0);
            }
        }

        __syncthreads();                       // all waves done reading tile mt
        if (mt < 7) STAGE_WRITE(p0, p1, p2, p3)
        __syncthreads();                       // tile mt+1 visible
    }

    // ---- epilogue ----
    // W loads early (hide under reduction)
    const float* wrp = W + (4 * mq) * FF + 4 * fq;
    f32x4 w0 = *(const f32x4*)(wrp);
    f32x4 w1 = *(const f32x4*)(wrp + FF);
    f32x4 w2 = *(const f32x4*)(wrp + 2 * FF);
    f32x4 w3 = *(const f32x4*)(wrp + 3 * FF);

    // deferred l reduction: row sum lives across the 32 lanes of each half
    float linv[16];
    #pragma unroll
    for (int r = 0; r < 16; ++r) {
        float v = lp[r];
        v += __shfl_xor(v, 1);
        v += __shfl_xor(v, 2);
        v += __shfl_xor(v, 4);
        v += __shfl_xor(v, 8);
        v += __shfl_xor(v, 16);
        linv[r] = 0.125f / v;                 // fold post-softmax 1/8 scale
    }

    // normalized agg (hi/lo) -> sA
    #pragma unroll
    for (int r = 0; r < 16; ++r) {
        int row = 32 * w + (r & 3) + 8 * (r >> 2) + 4 * hi2;
        float v0 = agg0[r] * linv[r];
        float v1 = agg1[r] * linv[r];
        short h0 = f2bf(v0); short g0 = f2bf(v0 - bf2f(h0));
        short h1 = f2bf(v1); short g1 = f2bf(v1 - bf2f(h1));
        *(short*)(sAH + (row * 68 + l31) * 2)      = h0;
        *(short*)(sAL + (row * 68 + l31) * 2)      = g0;
        *(short*)(sAH + (row * 68 + 32 + l31) * 2) = h1;
        *(short*)(sAL + (row * 68 + 32 + l31) * 2) = g1;
    }
    // W (hi/lo) -> sW
    {
        short4v h0,q0,h1,q1,h2,q2,h3,q3;
        cvt4(w0,h0,q0); cvt4(w1,h1,q1); cvt4(w2,h2,q2); cvt4(w3,h3,q3);
        *(short4v*)(sWH + ((4*mq+0)*72 + 4*fq) * 2) = h0;
        *(short4v*)(sWH + ((4*mq+1)*72 + 4*fq) * 2) = h1;
        *(short4v*)(sWH + ((4*mq+2)*72 + 4*fq) * 2) = h2;
        *(short4v*)(sWH + ((4*mq+3)*72 + 4*fq) * 2) = h3;
        *(short4v*)(sWL + ((4*mq+0)*72 + 4*fq) * 2) = q0;
        *(short4v*)(sWL + ((4*mq+1)*72 + 4*fq) * 2) = q1;
        *(short4v*)(sWL + ((4*mq+2)*72 + 4*fq) * 2) = q2;
        *(short4v*)(sWL + ((4*mq+3)*72 + 4*fq) * 2) = q3;
    }
    __syncthreads();

    // out = relu(agg_norm * W^T) via 3-term MFMA
    short8v gH[4], gL[4];
    #pragma unroll
    for (int ks = 0; ks < 4; ++ks) {
        short4v a0 = *(const short4v*)(sAH + ((32*w + l31) * 68 + ks*16 + hi2*8) * 2);
        short4v a1 = *(const short4v*)(sAH + ((32*w + l31) * 68 + ks*16 + hi2*8 + 4) * 2);
        short4v c0 = *(const short4v*)(sAL + ((32*w + l31) * 68 + ks*16 + hi2*8) * 2);
        short4v c1 = *(const short4v*)(sAL + ((32*w + l31) * 68 + ks*16 + hi2*8 + 4) * 2);
        gH[ks] = cat44(a0, a1);
        gL[ks] = cat44(c0, c1);
    }
    #pragma unroll
    for (int ob = 0; ob < 2; ++ob) {
        f32x16 oc;
        #pragma unroll
        for (int i = 0; i < 16; ++i) oc[i] = 0.f;
        #pragma unroll
        for (int ks = 0; ks < 4; ++ks) {
            short8v wH = *(const short8v*)(sWH + ((32*ob + l31) * 72 + ks*16 + hi2*8) * 2);
            short8v wL = *(const short8v*)(sWL + ((32*ob + l31) * 72 + ks*16 + hi2*8) * 2);
            oc = __builtin_amdgcn_mfma_f32_32x32x16_bf16(gH[ks], wH, oc, 0, 0, 0);
            oc = __builtin_amdgcn_mfma_f32_32x32x16_bf16(gH[ks], wL, oc, 0, 0, 0);
            oc = __builtin_amdgcn_mfma_f32_32x32x16_bf16(gL[ks], wH, oc, 0, 0, 0);
        }
        #pragma unroll
        for (int r = 0; r < 16; ++r) {
            int row = 32 * w + (r & 3) + 8 * (r >> 2) + 4 * hi2;
            out[((size_t)(b * NN + n0 + row) * TT + t) * FF + 32 * ob + l31] = fmaxf(oc[r], 0.f);
        }
    }
#undef STAGE_WRITE
}

extern "C" void kernel_launch(void* const* d_in, const int* in_sizes, int n_in,
                              void* d_out, int out_size, void* d_ws, size_t ws_size,
                              hipStream_t stream) {
    const float* x   = (const float*)d_in[0];
    const float* adj = (const float*)d_in[1];
    const float* W   = (const float*)d_in[2];
    float* outp = (float*)d_out;

    sgcn6<<<dim3(1536), dim3(256), 0, stream>>>(x, adj, W, outp);
}

// Round 7
// 137.394 us; speedup vs baseline: 1.8479x; 1.4206x over previous
//
#include <hip/hip_runtime.h>
#include <math.h>

// B,N,T,F = 32,512,12,64
#define NN 512
#define TT 12
#define FF 64

typedef float  f32x4   __attribute__((ext_vector_type(4)));
typedef float  f32x16  __attribute__((ext_vector_type(16)));
typedef short  short4v __attribute__((ext_vector_type(4)));
typedef short  short8v __attribute__((ext_vector_type(8)));
typedef unsigned int u32;
typedef u32    u32x2   __attribute__((ext_vector_type(2)));
typedef u32    u32x4   __attribute__((ext_vector_type(4)));

static __device__ __forceinline__ u32 cvtpk(float a, float b) {
    u32 p;
    asm("v_cvt_pk_bf16_f32 %0, %1, %2" : "=v"(p) : "v"(a), "v"(b));
    return p;   // low16 = bf16(a), high16 = bf16(b)
}
static __device__ __forceinline__ short f2bf(float f) {
    u32 u = __builtin_bit_cast(u32, f);
    u32 r = u + 0x7FFFu + ((u >> 16) & 1u);   // RNE
    return (short)(r >> 16);
}
static __device__ __forceinline__ float bf2f(short h) {
    u32 u = ((u32)(unsigned short)h) << 16;
    return __builtin_bit_cast(float, u);
}
static __device__ __forceinline__ void cvt4(f32x4 v, short4v& h, short4v& lo) {
    u32 p01 = cvtpk(v[0], v[1]);
    u32 p23 = cvtpk(v[2], v[3]);
    float r0 = v[0] - __builtin_bit_cast(float, p01 << 16);
    float r1 = v[1] - __builtin_bit_cast(float, p01 & 0xffff0000u);
    float r2 = v[2] - __builtin_bit_cast(float, p23 << 16);
    float r3 = v[3] - __builtin_bit_cast(float, p23 & 0xffff0000u);
    u32 q01 = cvtpk(r0, r1);
    u32 q23 = cvtpk(r2, r3);
    u32x2 hh; hh[0] = p01; hh[1] = p23;
    u32x2 qq; qq[0] = q01; qq[1] = q23;
    h  = __builtin_bit_cast(short4v, hh);
    lo = __builtin_bit_cast(short4v, qq);
}
static __device__ __forceinline__ short8v cat44(short4v a, short4v b) {
    return __builtin_shufflevector(a, b, 0, 1, 2, 3, 4, 5, 6, 7);
}

// LDS (bytes), total 35840 -> 4 blocks/CU:
//  main loop : sKH [64][72] @0      sKL @9216      (row-major K tile)
//              sKTH[64][68] @18432  sKTL @27136    (f-major V tile)
//  epilogue  : sAH [128][68] @0     sAL @17408     (normalized agg hi/lo)
//              linv f32[128] @34816
#define SMEM_BYTES 35840

__global__ __launch_bounds__(256, 4)
void sgcn7(const float* __restrict__ x, const float* __restrict__ adj,
           const float* __restrict__ W, float* __restrict__ out)
{
    __shared__ __align__(16) char smem[SMEM_BYTES];
    char* sKH  = smem;
    char* sKL  = smem + 9216;
    char* sKTH = smem + 18432;
    char* sKTL = smem + 27136;
    char* sAH  = smem;
    char* sAL  = smem + 17408;
    float* linvLDS = (float*)(smem + 34816);

    // XCD-grouped swizzle: 4 WGs per (b,t) adjacent on one XCD
    const int d   = blockIdx.x;
    const int xcd = d & 7;
    const int s   = d >> 3;
    const int G   = xcd + 8 * (s >> 2);   // 0..383 = b*12 + t
    const int mem = s & 3;
    const int t = G % TT, b = G / TT;
    const int n0 = mem * 128;

    const int tid = threadIdx.x;
    const int w   = tid >> 6;             // wave -> n-rows 32w..32w+31
    const int l31 = tid & 31;
    const int hi2 = (tid >> 5) & 1;
    const int fq  = tid & 15;             // staging: f-quad
    const int mq  = tid >> 4;             // staging: m-quad
    const int myn = n0 + 32 * w + l31;    // this lane's n (S^T col / PV A row)

    const float K2 = 0.18033688011112042f;   // 0.125 * log2(e)

#define STAGE_WRITE(L0, L1, L2, L3)                                            \
  {                                                                            \
    short4v h0,q0,h1,q1,h2,q2,h3,q3;                                           \
    cvt4(L0,h0,q0); cvt4(L1,h1,q1); cvt4(L2,h2,q2); cvt4(L3,h3,q3);            \
    *(short4v*)(sKH + ((4*mq+0)*72 + 4*fq) * 2) = h0;                          \
    *(short4v*)(sKH + ((4*mq+1)*72 + 4*fq) * 2) = h1;                          \
    *(short4v*)(sKH + ((4*mq+2)*72 + 4*fq) * 2) = h2;                          \
    *(short4v*)(sKH + ((4*mq+3)*72 + 4*fq) * 2) = h3;                          \
    *(short4v*)(sKL + ((4*mq+0)*72 + 4*fq) * 2) = q0;                          \
    *(short4v*)(sKL + ((4*mq+1)*72 + 4*fq) * 2) = q1;                          \
    *(short4v*)(sKL + ((4*mq+2)*72 + 4*fq) * 2) = q2;                          \
    *(short4v*)(sKL + ((4*mq+3)*72 + 4*fq) * 2) = q3;                          \
    _Pragma("unroll")                                                          \
    for (int j = 0; j < 4; ++j) {                                              \
        short4v th; th[0]=h0[j]; th[1]=h1[j]; th[2]=h2[j]; th[3]=h3[j];        \
        short4v tl; tl[0]=q0[j]; tl[1]=q1[j]; tl[2]=q2[j]; tl[3]=q3[j];        \
        *(short4v*)(sKTH + ((4*fq+j)*68 + 4*mq) * 2) = th;                     \
        *(short4v*)(sKTL + ((4*fq+j)*68 + 4*mq) * 2) = tl;                     \
    }                                                                          \
  }

    // ---- prologue: xn fragments (B-operand of S^T) + tile-0 staging ----
    const float* xnrow = x + ((size_t)(b * NN + myn) * TT + t) * FF;
    f32x4 xa[8];
    #pragma unroll
    for (int ks = 0; ks < 4; ++ks) {
        xa[2*ks]   = *(const f32x4*)(xnrow + ks * 16 + hi2 * 8);
        xa[2*ks+1] = *(const f32x4*)(xnrow + ks * 16 + hi2 * 8 + 4);
    }
    const float* xst = x + ((size_t)(b * NN + 4 * mq) * TT + t) * FF + 4 * fq;
    f32x4 ld0 = *(const f32x4*)(xst);
    f32x4 ld1 = *(const f32x4*)(xst + TT * FF);
    f32x4 ld2 = *(const f32x4*)(xst + 2 * TT * FF);
    f32x4 ld3 = *(const f32x4*)(xst + 3 * TT * FF);

    short8v xnH[4], xnL[4];
    #pragma unroll
    for (int ks = 0; ks < 4; ++ks) {
        short4v h0, l0, h1, l1;
        cvt4(xa[2*ks],   h0, l0);
        cvt4(xa[2*ks+1], h1, l1);
        xnH[ks] = cat44(h0, h1);
        xnL[ks] = cat44(l0, l1);
    }
    STAGE_WRITE(ld0, ld1, ld2, ld3)
    __syncthreads();

    float lpart = 0.f;
    f32x16 agg0, agg1;
    #pragma unroll
    for (int i = 0; i < 16; ++i) { agg0[i] = 0.f; agg1[i] = 0.f; }

    for (int mt = 0; mt < 8; ++mt) {
        const int m0 = mt * 64;

        // T14: issue next-tile loads now; convert+write after the barrier
        f32x4 p0, p1, p2, p3;
        if (mt < 7) {
            const float* xs = x + ((size_t)(b * NN + m0 + 64 + 4 * mq) * TT + t) * FF + 4 * fq;
            p0 = *(const f32x4*)(xs);
            p1 = *(const f32x4*)(xs + TT * FF);
            p2 = *(const f32x4*)(xs + 2 * TT * FF);
            p3 = *(const f32x4*)(xs + 3 * TT * FF);
        }

        // ---- S^T = Xm*Xn^T (A = K rows from LDS, B = xn regs) ----
        // D: col = n = l31 (lane), row = m = mb*32 + (r&3)+8*(r>>2)+4*hi2 (regs)
        short8v pa[4];
        #pragma unroll
        for (int mb = 0; mb < 2; ++mb) {
            const float* arow = adj + (size_t)myn * NN + m0 + mb * 32 + 4 * hi2;
            f32x4 av0 = *(const f32x4*)(arow);
            f32x4 av1 = *(const f32x4*)(arow + 8);
            f32x4 av2 = *(const f32x4*)(arow + 16);
            f32x4 av3 = *(const f32x4*)(arow + 24);

            f32x16 sc;
            #pragma unroll
            for (int i = 0; i < 16; ++i) sc[i] = 0.f;
            #pragma unroll
            for (int ks = 0; ks < 4; ++ks) {
                short8v kH = *(const short8v*)(sKH + ((mb*32 + l31) * 72 + ks*16 + hi2*8) * 2);
                short8v kL = *(const short8v*)(sKL + ((mb*32 + l31) * 72 + ks*16 + hi2*8) * 2);
                sc = __builtin_amdgcn_mfma_f32_32x32x16_bf16(kH, xnH[ks], sc, 0, 0, 0);
                sc = __builtin_amdgcn_mfma_f32_32x32x16_bf16(kH, xnL[ks], sc, 0, 0, 0);
                sc = __builtin_amdgcn_mfma_f32_32x32x16_bf16(kL, xnH[ks], sc, 0, 0, 0);
            }

            // maxless softmax, fully lane-local (denominator WITHOUT adj)
            float p[16];
            #pragma unroll
            for (int r = 0; r < 16; ++r) {
                p[r] = exp2f(sc[r] * K2);
                lpart += p[r];
            }
            p[0]  *= av0[0]; p[1]  *= av0[1]; p[2]  *= av0[2]; p[3]  *= av0[3];
            p[4]  *= av1[0]; p[5]  *= av1[1]; p[6]  *= av1[2]; p[7]  *= av1[3];
            p[8]  *= av2[0]; p[9]  *= av2[1]; p[10] *= av2[2]; p[11] *= av2[3];
            p[12] *= av3[0]; p[13] *= av3[1]; p[14] *= av3[2]; p[15] *= av3[3];

            // P (n=lane, m=regs) -> PV A-frag (row=n=lane, k=m) via half-exchange
            u32 A0 = cvtpk(p[0],  p[1]),  A1 = cvtpk(p[2],  p[3]);    // m: base+0..3
            u32 B0 = cvtpk(p[4],  p[5]),  B1 = cvtpk(p[6],  p[7]);    // m: base+8..11
            u32 A2 = cvtpk(p[8],  p[9]),  A3 = cvtpk(p[10], p[11]);   // m: base+16..19
            u32 B2 = cvtpk(p[12], p[13]), B3 = cvtpk(p[14], p[15]);   // m: base+24..27
            u32 sA0 = (u32)__shfl_xor((int)A0, 32), sA1 = (u32)__shfl_xor((int)A1, 32);
            u32 sB0 = (u32)__shfl_xor((int)B0, 32), sB1 = (u32)__shfl_xor((int)B1, 32);
            u32 sA2 = (u32)__shfl_xor((int)A2, 32), sA3 = (u32)__shfl_xor((int)A3, 32);
            u32 sB2 = (u32)__shfl_xor((int)B2, 32), sB3 = (u32)__shfl_xor((int)B3, 32);
            u32x4 e, o;
            e[0] = hi2 ? sB0 : A0;  e[1] = hi2 ? sB1 : A1;
            e[2] = hi2 ? B0 : sA0;  e[3] = hi2 ? B1 : sA1;
            o[0] = hi2 ? sB2 : A2;  o[1] = hi2 ? sB3 : A3;
            o[2] = hi2 ? B2 : sA2;  o[3] = hi2 ? B3 : sA3;
            pa[2*mb]     = __builtin_bit_cast(short8v, e);
            pa[2*mb + 1] = __builtin_bit_cast(short8v, o);
        }

        // ---- PV: agg[n][f] += P * V (B-frags = rows of f-major tile) ----
        #pragma unroll
        for (int ks = 0; ks < 4; ++ks) {
            {   // f-block 0 -> agg0
                short4v v0 = *(const short4v*)(sKTH + (l31 * 68 + ks*16 + hi2*8) * 2);
                short4v v1 = *(const short4v*)(sKTH + (l31 * 68 + ks*16 + hi2*8 + 4) * 2);
                short4v u0 = *(const short4v*)(sKTL + (l31 * 68 + ks*16 + hi2*8) * 2);
                short4v u1 = *(const short4v*)(sKTL + (l31 * 68 + ks*16 + hi2*8 + 4) * 2);
                agg0 = __builtin_amdgcn_mfma_f32_32x32x16_bf16(pa[ks], cat44(v0, v1), agg0, 0, 0, 0);
                agg0 = __builtin_amdgcn_mfma_f32_32x32x16_bf16(pa[ks], cat44(u0, u1), agg0, 0, 0, 0);
            }
            {   // f-block 1 -> agg1
                short4v v0 = *(const short4v*)(sKTH + ((32 + l31) * 68 + ks*16 + hi2*8) * 2);
                short4v v1 = *(const short4v*)(sKTH + ((32 + l31) * 68 + ks*16 + hi2*8 + 4) * 2);
                short4v u0 = *(const short4v*)(sKTL + ((32 + l31) * 68 + ks*16 + hi2*8) * 2);
                short4v u1 = *(const short4v*)(sKTL + ((32 + l31) * 68 + ks*16 + hi2*8 + 4) * 2);
                agg1 = __builtin_amdgcn_mfma_f32_32x32x16_bf16(pa[ks], cat44(v0, v1), agg1, 0, 0, 0);
                agg1 = __builtin_amdgcn_mfma_f32_32x32x16_bf16(pa[ks], cat44(u0, u1), agg1, 0, 0, 0);
            }
        }

        __syncthreads();                       // all waves done reading tile mt
        if (mt < 7) STAGE_WRITE(p0, p1, p2, p3)
        __syncthreads();                       // tile mt+1 visible
    }

    // ---- epilogue (barrier-free: all LDS traffic is wave-private) ----
    float lf = lpart + __shfl_xor(lpart, 32);
    if (hi2 == 0) linvLDS[32 * w + l31] = 0.125f / lf;   // fold post-softmax 1/8

    // normalized agg (hi/lo) -> sA  (agg: n in regs, f = lane; round-6 layout)
    #pragma unroll
    for (int r = 0; r < 16; ++r) {
        int row = 32 * w + (r & 3) + 8 * (r >> 2) + 4 * hi2;
        float nv = linvLDS[row];
        float v0 = agg0[r] * nv;
        float v1 = agg1[r] * nv;
        short h0 = f2bf(v0); short g0 = f2bf(v0 - bf2f(h0));
        short h1 = f2bf(v1); short g1 = f2bf(v1 - bf2f(h1));
        *(short*)(sAH + (row * 68 + l31) * 2)      = h0;
        *(short*)(sAL + (row * 68 + l31) * 2)      = g0;
        *(short*)(sAH + (row * 68 + 32 + l31) * 2) = h1;
        *(short*)(sAL + (row * 68 + 32 + l31) * 2) = g1;
    }

    // A-frags: lane = n reads its own row's f-slices (round-6 verified)
    short8v gH[4], gL[4];
    #pragma unroll
    for (int ks = 0; ks < 4; ++ks) {
        short4v a0 = *(const short4v*)(sAH + ((32*w + l31) * 68 + ks*16 + hi2*8) * 2);
        short4v a1 = *(const short4v*)(sAH + ((32*w + l31) * 68 + ks*16 + hi2*8 + 4) * 2);
        short4v c0 = *(const short4v*)(sAL + ((32*w + l31) * 68 + ks*16 + hi2*8) * 2);
        short4v c1 = *(const short4v*)(sAL + ((32*w + l31) * 68 + ks*16 + hi2*8 + 4) * 2);
        gH[ks] = cat44(a0, a1);
        gL[ks] = cat44(c0, c1);
    }

    // out = relu(aggN * W^T): B = W[k=f][col=o=lane] -> each lane holds its W row
    #pragma unroll
    for (int ob = 0; ob < 2; ++ob) {
        short8v wHreg[4], wLreg[4];
        #pragma unroll
        for (int ks = 0; ks < 4; ++ks) {
            const float* wp = W + (size_t)(ob * 32 + l31) * FF + ks * 16 + hi2 * 8;
            f32x4 wa = *(const f32x4*)(wp);
            f32x4 wb = *(const f32x4*)(wp + 4);
            short4v h0, l0, h1, l1;
            cvt4(wa, h0, l0);
            cvt4(wb, h1, l1);
            wHreg[ks] = cat44(h0, h1);
            wLreg[ks] = cat44(l0, l1);
        }
        f32x16 oc;
        #pragma unroll
        for (int i = 0; i < 16; ++i) oc[i] = 0.f;
        #pragma unroll
        for (int ks = 0; ks < 4; ++ks) {
            oc = __builtin_amdgcn_mfma_f32_32x32x16_bf16(gH[ks], wHreg[ks], oc, 0, 0, 0);
            oc = __builtin_amdgcn_mfma_f32_32x32x16_bf16(gH[ks], wLreg[ks], oc, 0, 0, 0);
            oc = __builtin_amdgcn_mfma_f32_32x32x16_bf16(gL[ks], wHreg[ks], oc, 0, 0, 0);
        }
        #pragma unroll
        for (int r = 0; r < 16; ++r) {
            int row = 32 * w + (r & 3) + 8 * (r >> 2) + 4 * hi2;
            out[((size_t)(b * NN + n0 + row) * TT + t) * FF + 32 * ob + l31] = fmaxf(oc[r], 0.f);
        }
    }
#undef STAGE_WRITE
}

extern "C" void kernel_launch(void* const* d_in, const int* in_sizes, int n_in,
                              void* d_out, int out_size, void* d_ws, size_t ws_size,
                              hipStream_t stream) {
    const float* x   = (const float*)d_in[0];
    const float* adj = (const float*)d_in[1];
    const float* W   = (const float*)d_in[2];
    float* outp = (float*)d_out;

    sgcn7<<<dim3(1536), dim3(256), 0, stream>>>(x, adj, W, outp);
}